// Round 5
// baseline (71.680 us; speedup 1.0000x reference)
//
#include <hip/hip_runtime.h>
#include <math.h>

// Problem constants (fixed by the reference)
constexpr int IN_DIM  = 128;
constexpr int OUT_DIM = 128;
constexpr int BATCH   = 512;
// Tiling: block = 64 n x 32 o x 16 i; thread = 4n x 2o (8 acc)
// grid = 8 n-tiles x 4 o-tiles x 8 i-chunks = 256 blocks (1/CU)
constexpr int TNT = 64;
constexpr int TOT = 32;
constexpr int IC  = 16;
constexpr int NCHUNK = 8;
constexpr int TOP = TOT + 1;  // padding breaks transpose-store bank conflicts

// out[n,o] = sum_i mask[s]*( scale_base[s]*silu(x[n,i])
//                          + scale_sp[s]*sum_j B_j(x[n,i])*coef[s,j] ), s=o*128+i
// Register blocking 4n x 2o: LDS bytes/FMA = 36(nR+oR)/(9 nR oR) = 3 (was 6),
// halving the LDS-pipe floor (453 -> 227 MB total LDS reads).
__global__ __launch_bounds__(256, 2) void kan_main(
    const float* __restrict__ x,          // [512][128]
    const float* __restrict__ grid,       // [16384][6] (rows identical)
    const float* __restrict__ coef,       // [16384][8]
    const float* __restrict__ scale_base, // [16384]
    const float* __restrict__ scale_sp,   // [16384]
    const float* __restrict__ mask,       // [16384]
    float* __restrict__ part)             // [8][512][128] partials in d_ws
{
    __shared__ float4 Cs0[IC * TOP];       // coef j0..3 * ssp * mask, [i][o] pad (8.4 KB)
    __shared__ float4 Cs1[IC * TOP];       // coef j4..7                          (8.4 KB)
    __shared__ float4 Ps4[TNT * IC * 2];   // basis fragments [n][i][2]           (32 KB)
    __shared__ float  Vb[IC * TOP];        // scale_base*mask, [i][o] pad         (2.1 KB)
    __shared__ float  Pb[IC * TNT];        // silu(x), [i][n]                     (4 KB)

    const int t  = threadIdx.x;
    const int b  = blockIdx.x;
    const int ic = b & 7;
    const int ot = (b >> 3) & 3;
    const int nt = b >> 5;
    const int i0 = ic * IC;
    const int o0 = ot * TOT;
    const int n0 = nt * TNT;

    // ---- knots from row 0 (all 16384 grid rows identical, uniform spacing h)
    const float g0 = grid[0];
    const float g5 = grid[5];
    const float h  = (g5 - g0) * 0.2f;
    float tk[12];
    tk[0] = g0 - 3.f * h; tk[1] = g0 - 2.f * h; tk[2] = g0 - h;
    tk[3] = grid[0]; tk[4] = grid[1]; tk[5] = grid[2];
    tk[6] = grid[3]; tk[7] = grid[4]; tk[8] = grid[5];
    tk[9] = g5 + h; tk[10] = g5 + 2.f * h; tk[11] = g5 + 3.f * h;
    // Uniform knots: every Cox-de Boor denominator is exactly r*h (the 1e-14
    // guard in the reference is a no-op). One divide replaces 54.
    const float inv1 = 1.0f / h;
    const float invr[3] = {inv1, inv1 * 0.5f, inv1 * (1.0f / 3.0f)};

    // ---- phase 1: basis + silu for 64 n x 16 i = 1024 pairs, 4/thread
    #pragma unroll
    for (int rep = 0; rep < 4; rep++) {
        const int p  = rep * 256 + t;
        const int nl = p >> 4;          // 0..63
        const int il = p & 15;
        const float xv = x[(n0 + nl) * IN_DIM + i0 + il];

        float B[11];
        #pragma unroll
        for (int j = 0; j < 11; j++)
            B[j] = (xv >= tk[j] && xv < tk[j + 1]) ? 1.0f : 0.0f;
        #pragma unroll
        for (int r = 1; r <= 3; r++) {
            const float iv = invr[r - 1];
            #pragma unroll
            for (int j = 0; j + r < 11; j++)
                B[j] = (xv - tk[j]) * iv * B[j] + (tk[j + r + 1] - xv) * iv * B[j + 1];
        }
        Ps4[(nl * IC + il) * 2 + 0] = make_float4(B[0], B[1], B[2], B[3]);
        Ps4[(nl * IC + il) * 2 + 1] = make_float4(B[4], B[5], B[6], B[7]);
        Pb[il * TNT + nl] = xv / (1.0f + __expf(-xv));   // silu, [i][n]
    }

    // ---- stage coef premultiplied by scale_sp*mask (32 o x 16 i x 2 = 1024 f4)
    #pragma unroll
    for (int rep = 0; rep < 4; rep++) {
        const int fi = rep * 256 + t;
        const int o  = fi >> 5;         // 0..31
        const int w  = fi & 31;
        const int i  = w >> 1;
        const int hh = w & 1;
        const int s  = (o0 + o) * IN_DIM + i0 + i;
        float4 c = ((const float4*)coef)[(size_t)s * 2 + hh];
        const float v = scale_sp[s] * mask[s];
        c.x *= v; c.y *= v; c.z *= v; c.w *= v;
        if (hh) Cs1[i * TOP + o] = c; else Cs0[i * TOP + o] = c;
    }
    // ---- stage scale_base*mask (32 o x 16 i = 512), [i][o] pad
    #pragma unroll
    for (int rep = 0; rep < 2; rep++) {
        const int v = rep * 256 + t;
        const int o = v >> 4;
        const int i = v & 15;
        const int s = (o0 + o) * IN_DIM + i0 + i;
        Vb[i * TOP + o] = scale_base[s] * mask[s];
    }
    __syncthreads();

    // ---- main: thread owns (n = q + r*16, r=0..3) x (o = o2, o2+16)
    const int o2 = t & 15;
    const int q  = t >> 4;      // 0..15
    float acc[4][2];
    #pragma unroll
    for (int r = 0; r < 4; r++) { acc[r][0] = 0.f; acc[r][1] = 0.f; }

    #pragma unroll
    for (int i = 0; i < IC; i++) {
        const float4 cA0 = Cs0[i * TOP + o2];
        const float4 cA1 = Cs1[i * TOP + o2];
        const float4 cB0 = Cs0[i * TOP + o2 + 16];
        const float4 cB1 = Cs1[i * TOP + o2 + 16];
        const float vbA  = Vb[i * TOP + o2];
        const float vbB  = Vb[i * TOP + o2 + 16];
        #pragma unroll
        for (int r = 0; r < 4; r++) {
            const int n = q + r * 16;
            const float4 p0 = Ps4[(n * IC + i) * 2 + 0];
            const float4 p1 = Ps4[(n * IC + i) * 2 + 1];
            const float pb  = Pb[i * TNT + n];
            acc[r][0] += p0.x * cA0.x + p0.y * cA0.y + p0.z * cA0.z + p0.w * cA0.w
                       + p1.x * cA1.x + p1.y * cA1.y + p1.z * cA1.z + p1.w * cA1.w
                       + vbA * pb;
            acc[r][1] += p0.x * cB0.x + p0.y * cB0.y + p0.z * cB0.z + p0.w * cB0.w
                       + p1.x * cB1.x + p1.y * cB1.y + p1.z * cB1.z + p1.w * cB1.w
                       + vbB * pb;
        }
    }

    // partial stores: 16-lane contiguous 64 B segments
    #pragma unroll
    for (int r = 0; r < 4; r++) {
        const int n = n0 + q + r * 16;
        part[((size_t)ic * BATCH + n) * OUT_DIM + o0 + o2]      = acc[r][0];
        part[((size_t)ic * BATCH + n) * OUT_DIM + o0 + o2 + 16] = acc[r][1];
    }
}

// Sum the 8 i-chunk partials. 64K cells, fully coalesced, L2-resident.
__global__ __launch_bounds__(256) void kan_reduce(
    const float* __restrict__ part,   // [8][65536]
    float* __restrict__ out)          // [65536]
{
    const int cell = blockIdx.x * 256 + threadIdx.x;
    float s = 0.f;
    #pragma unroll
    for (int c = 0; c < NCHUNK; c++)
        s += part[c * (BATCH * OUT_DIM) + cell];
    out[cell] = s;
}

extern "C" void kernel_launch(void* const* d_in, const int* in_sizes, int n_in,
                              void* d_out, int out_size, void* d_ws, size_t ws_size,
                              hipStream_t stream) {
    const float* x          = (const float*)d_in[0];
    const float* grid       = (const float*)d_in[1];
    const float* coef       = (const float*)d_in[2];
    const float* scale_base = (const float*)d_in[3];
    const float* scale_sp   = (const float*)d_in[4];
    const float* mask       = (const float*)d_in[5];
    float* out  = (float*)d_out;
    float* part = (float*)d_ws;   // 8*512*128*4 = 2 MB << ws_size

    // grid = 8 n-tiles x 4 o-tiles x 8 i-chunks = 256 blocks
    kan_main<<<dim3(256), dim3(256), 0, stream>>>(
        x, grid, coef, scale_base, scale_sp, mask, part);
    kan_reduce<<<dim3(BATCH * OUT_DIM / 256), dim3(256), 0, stream>>>(part, out);
}

// Round 6
// 71.638 us; speedup vs baseline: 1.0006x; 1.0006x over previous
//
#include <hip/hip_runtime.h>
#include <math.h>

// Problem constants (fixed by the reference)
constexpr int IN_DIM  = 128;
constexpr int OUT_DIM = 128;
constexpr int BATCH   = 512;
// Tiling: block = 32 n x 32 o x 16 i; thread = 2n x 2o (4 acc)
// grid = 16 n-tiles x 4 o-tiles x 8 i-chunks = 512 blocks (2/CU, 8 waves/CU)
constexpr int TNT = 32;
constexpr int TOT = 32;
constexpr int IC  = 16;
constexpr int NCHUNK = 8;
constexpr int TOP = TOT + 1;      // Cs/Vb row pad: breaks transpose-store conflicts
constexpr int PSW = IC * 2 + 1;   // Ps4 row pad (33 f4 = 528 B): n-broadcast rows
                                  // land 4 banks apart instead of aliasing (m136)

// out[n,o] = sum_i mask[s]*( scale_base[s]*silu(x[n,i])
//                          + scale_sp[s]*sum_j B_j(x[n,i])*coef[s,j] ), s=o*128+i
// 2n x 2o register blocking: 4 B/FMA LDS traffic (R4 was 6) while keeping
// 8 waves/CU (R5's 4 waves/CU was latency-bound: halved traffic, +1.1 us).
__global__ __launch_bounds__(256, 2) void kan_main(
    const float* __restrict__ x,          // [512][128]
    const float* __restrict__ grid,       // [16384][6] (rows identical)
    const float* __restrict__ coef,       // [16384][8]
    const float* __restrict__ scale_base, // [16384]
    const float* __restrict__ scale_sp,   // [16384]
    const float* __restrict__ mask,       // [16384]
    float* __restrict__ part)             // [8][512][128] partials in d_ws
{
    __shared__ float4 Cs0[IC * TOP];    // coef j0..3 * ssp * mask, [i][o] pad (8.4 KB)
    __shared__ float4 Cs1[IC * TOP];    // coef j4..7                         (8.4 KB)
    __shared__ float4 Ps4[TNT * PSW];   // basis fragments [n][2i+h], padded  (16.9 KB)
    __shared__ float  Vb[IC * TOP];     // scale_base*mask, [i][o] pad        (2.1 KB)
    __shared__ float  Pb[IC * TNT];     // silu(x), [i][n]                    (2 KB)

    const int t  = threadIdx.x;
    const int b  = blockIdx.x;
    const int ic = b & 7;
    const int ot = (b >> 3) & 3;
    const int nt = b >> 5;
    const int i0 = ic * IC;
    const int o0 = ot * TOT;
    const int n0 = nt * TNT;

    // ---- knots from row 0 (all 16384 grid rows identical, uniform spacing h)
    const float g0 = grid[0];
    const float g5 = grid[5];
    const float h  = (g5 - g0) * 0.2f;
    float tk[12];
    tk[0] = g0 - 3.f * h; tk[1] = g0 - 2.f * h; tk[2] = g0 - h;
    tk[3] = grid[0]; tk[4] = grid[1]; tk[5] = grid[2];
    tk[6] = grid[3]; tk[7] = grid[4]; tk[8] = grid[5];
    tk[9] = g5 + h; tk[10] = g5 + 2.f * h; tk[11] = g5 + 3.f * h;
    // Uniform knots: every Cox-de Boor denominator is exactly r*h (the 1e-14
    // guard in the reference is a no-op). One divide replaces 54.
    const float inv1 = 1.0f / h;
    const float invr[3] = {inv1, inv1 * 0.5f, inv1 * (1.0f / 3.0f)};

    // ---- phase 1: basis + silu for 32 n x 16 i = 512 pairs, 2/thread
    #pragma unroll
    for (int rep = 0; rep < 2; rep++) {
        const int p  = rep * 256 + t;
        const int nl = p >> 4;          // 0..31
        const int il = p & 15;
        const float xv = x[(n0 + nl) * IN_DIM + i0 + il];

        float B[11];
        #pragma unroll
        for (int j = 0; j < 11; j++)
            B[j] = (xv >= tk[j] && xv < tk[j + 1]) ? 1.0f : 0.0f;
        #pragma unroll
        for (int r = 1; r <= 3; r++) {
            const float iv = invr[r - 1];
            #pragma unroll
            for (int j = 0; j + r < 11; j++)
                B[j] = (xv - tk[j]) * iv * B[j] + (tk[j + r + 1] - xv) * iv * B[j + 1];
        }
        Ps4[nl * PSW + 2 * il + 0] = make_float4(B[0], B[1], B[2], B[3]);
        Ps4[nl * PSW + 2 * il + 1] = make_float4(B[4], B[5], B[6], B[7]);
        Pb[il * TNT + nl] = xv / (1.0f + __expf(-xv));   // silu, [i][n]
    }

    // ---- stage coef premultiplied by scale_sp*mask (32 o x 16 i x 2 = 1024 f4)
    #pragma unroll
    for (int rep = 0; rep < 4; rep++) {
        const int fi = rep * 256 + t;
        const int o  = fi >> 5;         // 0..31
        const int w  = fi & 31;
        const int i  = w >> 1;
        const int hh = w & 1;
        const int s  = (o0 + o) * IN_DIM + i0 + i;
        float4 c = ((const float4*)coef)[(size_t)s * 2 + hh];
        const float v = scale_sp[s] * mask[s];
        c.x *= v; c.y *= v; c.z *= v; c.w *= v;
        if (hh) Cs1[i * TOP + o] = c; else Cs0[i * TOP + o] = c;
    }
    // ---- stage scale_base*mask (32 o x 16 i = 512), [i][o] pad
    #pragma unroll
    for (int rep = 0; rep < 2; rep++) {
        const int v = rep * 256 + t;
        const int o = v >> 4;
        const int i = v & 15;
        const int s = (o0 + o) * IN_DIM + i0 + i;
        Vb[i * TOP + o] = scale_base[s] * mask[s];
    }
    __syncthreads();

    // ---- main: thread owns (n = q, q+16) x (o = o2, o2+16); 4 indep chains
    const int o2 = t & 15;
    const int q  = t >> 4;      // 0..15
    float a00 = 0.f, a01 = 0.f, a10 = 0.f, a11 = 0.f;

    #pragma unroll
    for (int i = 0; i < IC; i++) {
        const float4 cA0 = Cs0[i * TOP + o2];
        const float4 cA1 = Cs1[i * TOP + o2];
        const float4 cB0 = Cs0[i * TOP + o2 + 16];
        const float4 cB1 = Cs1[i * TOP + o2 + 16];
        const float vbA  = Vb[i * TOP + o2];
        const float vbB  = Vb[i * TOP + o2 + 16];

        const float4 p00 = Ps4[q * PSW + 2 * i + 0];
        const float4 p01 = Ps4[q * PSW + 2 * i + 1];
        const float4 p10 = Ps4[(q + 16) * PSW + 2 * i + 0];
        const float4 p11 = Ps4[(q + 16) * PSW + 2 * i + 1];
        const float pb0  = Pb[i * TNT + q];
        const float pb1  = Pb[i * TNT + q + 16];

        a00 += p00.x * cA0.x + p00.y * cA0.y + p00.z * cA0.z + p00.w * cA0.w
             + p01.x * cA1.x + p01.y * cA1.y + p01.z * cA1.z + p01.w * cA1.w
             + vbA * pb0;
        a01 += p00.x * cB0.x + p00.y * cB0.y + p00.z * cB0.z + p00.w * cB0.w
             + p01.x * cB1.x + p01.y * cB1.y + p01.z * cB1.z + p01.w * cB1.w
             + vbB * pb0;
        a10 += p10.x * cA0.x + p10.y * cA0.y + p10.z * cA0.z + p10.w * cA0.w
             + p11.x * cA1.x + p11.y * cA1.y + p11.z * cA1.z + p11.w * cA1.w
             + vbA * pb1;
        a11 += p10.x * cB0.x + p10.y * cB0.y + p10.z * cB0.z + p10.w * cB0.w
             + p11.x * cB1.x + p11.y * cB1.y + p11.z * cB1.z + p11.w * cB1.w
             + vbB * pb1;
    }

    // partial stores: 16-lane contiguous 64 B segments
    {
        const size_t base = (size_t)ic * BATCH * OUT_DIM;
        part[base + (size_t)(n0 + q)      * OUT_DIM + o0 + o2]      = a00;
        part[base + (size_t)(n0 + q)      * OUT_DIM + o0 + o2 + 16] = a01;
        part[base + (size_t)(n0 + q + 16) * OUT_DIM + o0 + o2]      = a10;
        part[base + (size_t)(n0 + q + 16) * OUT_DIM + o0 + o2 + 16] = a11;
    }
}

// Sum the 8 i-chunk partials. float4 lanes: 16K threads, L2-resident.
__global__ __launch_bounds__(256) void kan_reduce(
    const float4* __restrict__ part,   // [8][16384] f4
    float4* __restrict__ out)          // [16384] f4
{
    const int cell = blockIdx.x * 256 + threadIdx.x;
    float4 s = part[cell];
    #pragma unroll
    for (int c = 1; c < NCHUNK; c++) {
        const float4 v = part[c * (BATCH * OUT_DIM / 4) + cell];
        s.x += v.x; s.y += v.y; s.z += v.z; s.w += v.w;
    }
    out[cell] = s;
}

extern "C" void kernel_launch(void* const* d_in, const int* in_sizes, int n_in,
                              void* d_out, int out_size, void* d_ws, size_t ws_size,
                              hipStream_t stream) {
    const float* x          = (const float*)d_in[0];
    const float* grid       = (const float*)d_in[1];
    const float* coef       = (const float*)d_in[2];
    const float* scale_base = (const float*)d_in[3];
    const float* scale_sp   = (const float*)d_in[4];
    const float* mask       = (const float*)d_in[5];
    float* out  = (float*)d_out;
    float* part = (float*)d_ws;   // 8*512*128*4 = 2 MB << ws_size

    // grid = 16 n-tiles x 4 o-tiles x 8 i-chunks = 512 blocks (2/CU)
    kan_main<<<dim3(512), dim3(256), 0, stream>>>(
        x, grid, coef, scale_base, scale_sp, mask, part);
    kan_reduce<<<dim3(BATCH * OUT_DIM / 4 / 256), dim3(256), 0, stream>>>(
        (const float4*)part, (float4*)out);
}